// Round 10
// baseline (644.867 us; speedup 1.0000x reference)
//
#include <hip/hip_runtime.h>

#define N_NODES 100000
#define N_EDGES 1600000
#define FEAT 128
#define KB 256      // coarse buckets for edge partition (node ranges)
#define BCAP 8192   // padded capacity per bucket (mean 6250)
#define TILE 2048   // edges per fillA block
#define NPB 400     // max nodes per bucket (391) padded
#define CGRID 512   // persistent blocks for layer-4 GEMMs (2 per CU)

typedef short bf16x8 __attribute__((ext_vector_type(8)));
typedef float f32x4 __attribute__((ext_vector_type(4)));

__device__ __forceinline__ ushort f2bf(float x) {
    union { float f; unsigned int u; } v; v.f = x;
    unsigned int u = v.u;
    return (ushort)((u + 0x7fffu + ((u >> 16) & 1u)) >> 16);  // RNE
}
__device__ __forceinline__ float bf2f(ushort h) {
    union { float f; unsigned int u; } v; v.u = ((unsigned int)h) << 16;
    return v.f;
}
__device__ __forceinline__ float lo16f(unsigned int u) {
    union { float f; unsigned int u; } v; v.u = u << 16;
    return v.f;
}
__device__ __forceinline__ float hi16f(unsigned int u) {
    union { float f; unsigned int u; } v; v.u = u & 0xffff0000u;
    return v.f;
}

#define MFMA(a, b, c) __builtin_amdgcn_mfma_f32_16x16x32_bf16((a), (b), (c), 0, 0, 0)

// async global->LDS, 16B per lane. dest = wave-uniform base + lane*16.
#define GLOAD_LDS16(g, l)                                                       \
    __builtin_amdgcn_global_load_lds(                                           \
        (const __attribute__((address_space(1))) unsigned int*)(g),             \
        (__attribute__((address_space(3))) unsigned int*)(l), 16, 0, 0)

// ---------------- CSR build ----------------

// fillA: per block, LDS count -> reserve run (1 global atomic/bucket) ->
// direct scatter into padded buckets. gcur zeroed by hipMemsetAsync.
__global__ __launch_bounds__(256) void fillA_kernel(const int* __restrict__ src,
                                                    const int* __restrict__ dst,
                                                    int* __restrict__ gcur,
                                                    int2* __restrict__ pairs) {
    __shared__ int cnt[KB];
    __shared__ int cur[KB];
    __shared__ int rbase[KB];
    int t = threadIdx.x;
    int base = blockIdx.x * TILE;
    cnt[t] = 0;
    __syncthreads();
    int myS[8], myD[8];
#pragma unroll
    for (int j = 0; j < 8; ++j) {
        int e = base + j * 256 + t;
        int s = 0, d = -1;
        if (e < N_EDGES) {
            s = src[e]; d = dst[e];
            int b = (int)(((unsigned)d * KB) / N_NODES);
            atomicAdd(&cnt[b], 1);
        }
        myS[j] = s; myD[j] = d;
    }
    __syncthreads();
    rbase[t] = atomicAdd(&gcur[t], cnt[t]);
    cur[t] = 0;
    __syncthreads();
#pragma unroll
    for (int j = 0; j < 8; ++j) {
        if (myD[j] >= 0) {
            int b = (int)(((unsigned)myD[j] * KB) / N_NODES);
            int slot = atomicAdd(&cur[b], 1);
            pairs[(size_t)b * BCAP + rbase[b] + slot] = make_int2(myS[j], myD[j]);
        }
    }
}

// fillB: one block per bucket; computes the global bucket prefix itself,
// then local hist + scan -> row + col.
__global__ __launch_bounds__(512) void fillB_kernel(const int2* __restrict__ pairs,
                                                    const int* __restrict__ gcur,
                                                    int* __restrict__ row,
                                                    int* __restrict__ col) {
    __shared__ int ssrc[BCAP];      // 32 KB
    __shared__ ushort ld16[BCAP];   // 16 KB
    __shared__ int lcnt[NPB], lex[NPB], lcur[NPB];
    __shared__ int sc[512];
    __shared__ int pre[KB];
    int b = blockIdx.x;
    int t = threadIdx.x;
    int n0 = (b * N_NODES + KB - 1) / KB;
    int n1 = ((b + 1) * N_NODES + KB - 1) / KB;
    if (n1 > N_NODES) n1 = N_NODES;
    int nn = n1 - n0;
    int cnt = gcur[b];
    if (cnt > BCAP) cnt = BCAP;
    if (t < NPB) { lcnt[t] = 0; lcur[t] = 0; }
    if (t < KB) pre[t] = gcur[t];
    __syncthreads();
    for (int off = 1; off < KB; off <<= 1) {
        int x = 0, y = 0;
        if (t < KB) { x = pre[t]; y = (t >= off) ? pre[t - off] : 0; }
        __syncthreads();
        if (t < KB) pre[t] = x + y;
        __syncthreads();
    }
    int cbase = (b == 0) ? 0 : pre[b - 1];
    const int2* bp = pairs + (size_t)b * BCAP;
    for (int i = t; i < cnt; i += 512) {
        int2 pr = bp[i];
        int ld = pr.y - n0;
        atomicAdd(&lcnt[ld], 1);
        ld16[i] = (ushort)ld;
        ssrc[i] = pr.x;
    }
    __syncthreads();
    int val = (t < nn) ? lcnt[t] : 0;
    sc[t] = val;
    __syncthreads();
    for (int off = 1; off < 512; off <<= 1) {
        int x = sc[t];
        int y = (t >= off) ? sc[t - off] : 0;
        __syncthreads();
        sc[t] = x + y;
        __syncthreads();
    }
    if (t < nn) {
        int ex = sc[t] - val;
        lex[t] = ex;
        row[n0 + t] = cbase + ex;
    }
    if (b == 0 && t == 0) row[N_NODES] = N_EDGES;
    __syncthreads();
    for (int i = t; i < cnt; i += 512) {
        int ld = ld16[i];
        int pos = cbase + lex[ld] + atomicAdd(&lcur[ld], 1);
        col[pos] = ssrc[i];
    }
}

// ---------------- converts ----------------

__global__ __launch_bounds__(256) void convert_x_kernel(const float* __restrict__ x,
                                                        ushort* __restrict__ xb) {
    int idx = (blockIdx.x * 256 + threadIdx.x) * 4;
    if (idx >= N_NODES * FEAT) return;
    float4 v = *(const float4*)(x + idx);
    ushort4 o;
    o.x = f2bf(v.x); o.y = f2bf(v.y); o.z = f2bf(v.z); o.w = f2bf(v.w);
    *(ushort4*)(xb + idx) = o;
}

// weights fp32 -> (hi, lo) bf16 planes, zero-padded to 128 rows.
__global__ __launch_bounds__(128) void convert_w_kernel(
    const float* w0, const float* w1, const float* w2, const float* w3,
    const float* w4, const float* w5, const float* w6, const float* w7,
    ushort* __restrict__ wp) {
    int m = blockIdx.y;
    int r = blockIdx.x;
    int c = threadIdx.x;
    const float* src;
    switch (m) {
        case 0: src = w0; break; case 1: src = w1; break;
        case 2: src = w2; break; case 3: src = w3; break;
        case 4: src = w4; break; case 5: src = w5; break;
        case 6: src = w6; break; default: src = w7; break;
    }
    int rows = (m >= 6) ? 40 : 128;
    float val = (r < rows) ? src[r * FEAT + c] : 0.f;
    ushort hi = f2bf(val);
    ushort lo = f2bf(val - bf2f(hi));
    wp[(size_t)m * 32768 + r * FEAT + c] = hi;
    wp[(size_t)m * 32768 + 16384 + r * FEAT + c] = lo;
}

// ---------------- fused layer v2 (layers 1-3) ----------------
// Round-9 post-mortem: fusion v1 cut gather TLP 8x (waves looped 8 nodes
// serially; VALUBusy 44->24, occ 70->36, 124us). v2 keeps agg's EXACT
// concurrency shape: one-shot 1024-thread blocks, 16 waves, ONE NODE PER
// WAVE (agg body verbatim -> bit-identical means), 6250 blocks for deep
// backfill. Then a short MFMA tail: 8 waves compute the 16x128 output tile
// from LDS self+agg rows (per-kt B loads, r8's 4-MFMA chain order). Self
// rows DMA'd by waves 0-3 at block top (hides under gather). Eliminates
// the 25.6MB aggB write + read-back and the combine dispatch per layer.

__global__ __launch_bounds__(1024) void fused_layer_kernel(
    const ushort* __restrict__ hb, const int* __restrict__ row,
    const int* __restrict__ col, const ushort* __restrict__ wp,
    const float* __restrict__ bias, ushort* __restrict__ outB, int doRelu) {
    __shared__ ushort smemH[16 * FEAT];  // 4KB, swizzled self rows
    __shared__ ushort smemA[16 * FEAT];  // 4KB, swizzled agg rows
    int tid = threadIdx.x;
    int lane = tid & 63;
    int w = tid >> 6;                // 0..15
    int g = lane >> 4;               // edge slot for gather
    int flOff = (lane & 15) * 16;    // feature-chunk byte offset
    int v0 = blockIdx.x * 16;

    const char* hp = (const char*)hb;
    char* shH = (char*)smemH;
    char* shA = (char*)smemA;

    // ---- (1) DMA self rows (4KB, source-swizzled), waves 0-3 ----
    if (w < 4) {
        const char* hpg = hp + (size_t)v0 * 256;
        int d = w * 1024 + lane * 16;
        int s = d ^ (((d >> 8) & 7) << 4);  // involution: LDS[x^swz]=G[x]
        GLOAD_LDS16(hpg + s, shH + w * 1024);
    }

    // ---- (2) gather-aggregate: wave w owns node v0+w (verbatim agg body) ----
    {
        int v = v0 + w;
        int beg = row[v], end = row[v + 1];
        int deg = end - beg;
        float a0 = 0.f, a1 = 0.f, a2 = 0.f, a3 = 0.f;
        float a4 = 0.f, a5 = 0.f, a6 = 0.f, a7 = 0.f;

#define ACC8(p)                                          \
    a0 += lo16f((p).x); a1 += hi16f((p).x);              \
    a2 += lo16f((p).y); a3 += hi16f((p).y);              \
    a4 += lo16f((p).z); a5 += hi16f((p).z);              \
    a6 += lo16f((p).w); a7 += hi16f((p).w);

        int i = beg;
        int end16 = beg + (deg & ~15);
        if (i < end16) {
            int c0 = col[i + g];
            int c1 = col[i + 4 + g];
            int c2 = col[i + 8 + g];
            int c3 = col[i + 12 + g];
            while (true) {
                uint4 p0 = *(const uint4*)(hp + (((unsigned)c0 << 8) | (unsigned)flOff));
                uint4 p1 = *(const uint4*)(hp + (((unsigned)c1 << 8) | (unsigned)flOff));
                uint4 p2 = *(const uint4*)(hp + (((unsigned)c2 << 8) | (unsigned)flOff));
                uint4 p3 = *(const uint4*)(hp + (((unsigned)c3 << 8) | (unsigned)flOff));
                i += 16;
                bool more = i < end16;
                if (more) {
                    c0 = col[i + g];
                    c1 = col[i + 4 + g];
                    c2 = col[i + 8 + g];
                    c3 = col[i + 12 + g];
                }
                ACC8(p0);
                ACC8(p1);
                ACC8(p2);
                ACC8(p3);
                if (!more) break;
            }
        }
        if (i + 8 <= end) {
            int c0 = col[i + g];
            int c1 = col[i + 4 + g];
            uint4 p0 = *(const uint4*)(hp + (((unsigned)c0 << 8) | (unsigned)flOff));
            uint4 p1 = *(const uint4*)(hp + (((unsigned)c1 << 8) | (unsigned)flOff));
            ACC8(p0);
            ACC8(p1);
            i += 8;
        }
        if (i + 4 <= end) {
            int c = col[i + g];
            uint4 p = *(const uint4*)(hp + (((unsigned)c << 8) | (unsigned)flOff));
            ACC8(p);
            i += 4;
        }
        if (i < end) {
            int e = i + g;
            bool ok = e < end;
            int c = col[ok ? e : beg];
            uint4 p = *(const uint4*)(hp + (((unsigned)c << 8) | (unsigned)flOff));
            float m = ok ? 1.f : 0.f;
            a0 += m * lo16f(p.x); a1 += m * hi16f(p.x);
            a2 += m * lo16f(p.y); a3 += m * hi16f(p.y);
            a4 += m * lo16f(p.z); a5 += m * hi16f(p.z);
            a6 += m * lo16f(p.w); a7 += m * hi16f(p.w);
        }
#undef ACC8

        a0 += __shfl_xor(a0, 16); a1 += __shfl_xor(a1, 16);
        a2 += __shfl_xor(a2, 16); a3 += __shfl_xor(a3, 16);
        a4 += __shfl_xor(a4, 16); a5 += __shfl_xor(a5, 16);
        a6 += __shfl_xor(a6, 16); a7 += __shfl_xor(a7, 16);
        a0 += __shfl_xor(a0, 32); a1 += __shfl_xor(a1, 32);
        a2 += __shfl_xor(a2, 32); a3 += __shfl_xor(a3, 32);
        a4 += __shfl_xor(a4, 32); a5 += __shfl_xor(a5, 32);
        a6 += __shfl_xor(a6, 32); a7 += __shfl_xor(a7, 32);
        if (g == 0) {
            float invd = 1.0f / (float)(deg > 0 ? deg : 1);
            uint4 o;
            o.x = (unsigned)f2bf(a0 * invd) | ((unsigned)f2bf(a1 * invd) << 16);
            o.y = (unsigned)f2bf(a2 * invd) | ((unsigned)f2bf(a3 * invd) << 16);
            o.z = (unsigned)f2bf(a4 * invd) | ((unsigned)f2bf(a5 * invd) << 16);
            o.w = (unsigned)f2bf(a6 * invd) | ((unsigned)f2bf(a7 * invd) << 16);
            int off = (w * 256 + flOff) ^ ((w & 7) << 4);  // same involution as reads
            *(uint4*)(shA + off) = o;
        }
    }

    __syncthreads();  // drains self-row DMA (vmcnt) + agg ds_writes (lgkm)

    // ---- (3) MFMA tail: waves 0-7, 16x16 output tile each ----
    if (w < 8) {
        int frow = lane & 15;
        int fq = lane >> 4;
        int fk = fq * 8;
        const ushort* sHi = wp;
        const ushort* sLo = wp + 16384;
        const ushort* nHi = wp + 32768;
        const ushort* nLo = wp + 49152;
        int n0 = w * 16 + frow;

        f32x4 acc = (f32x4)(0.f);
#pragma unroll 1
        for (int kt = 0; kt < 4; ++kt) {
            int k = kt * 32 + fk;
            bf16x8 Bsh = *(const bf16x8*)(sHi + n0 * FEAT + k);
            bf16x8 Bsl = *(const bf16x8*)(sLo + n0 * FEAT + k);
            bf16x8 Bnh = *(const bf16x8*)(nHi + n0 * FEAT + k);
            bf16x8 Bnl = *(const bf16x8*)(nLo + n0 * FEAT + k);
            int kB = kt * 64 + fq * 16;
            int off = ((frow << 8) + kB) ^ ((frow & 7) << 4);
            bf16x8 Ah = *(const bf16x8*)(shH + off);
            bf16x8 Aa = *(const bf16x8*)(shA + off);
            acc = MFMA(Ah, Bsh, acc);
            acc = MFMA(Ah, Bsl, acc);
            acc = MFMA(Aa, Bnh, acc);
            acc = MFMA(Aa, Bnl, acc);
        }

        int colo = w * 16 + (lane & 15);
        float b = bias[colo];
#pragma unroll
        for (int i = 0; i < 4; ++i) {
            int v = v0 + (lane >> 4) * 4 + i;
            float r = acc[i] + b;
            if (doRelu) r = fmaxf(r, 0.f);
            outB[(size_t)v * FEAT + colo] = f2bf(r);
        }
    }
}

// ---------------- layer 4: persistent project-then-aggregate ----------------

__global__ __launch_bounds__(256, 2) void proj_kernel(
    const ushort* __restrict__ hb, const ushort* __restrict__ wn,
    ushort* __restrict__ pbuf) {
    __shared__ ushort smem[2][128 * FEAT];  // 2 x 32KB, swizzled hb tiles
    int tid = threadIdx.x;
    int lane = tid & 63;
    int w = tid >> 6;
    int rh = w >> 1;          // row-half (0: rows 0-63, 1: rows 64-127)
    int nb = (w & 1) * 32;    // col-half of the 64 weight rows
    int frow = lane & 15;
    int fq = lane >> 4;
    int fk = fq * 8;
    const ushort* nHi = wn;
    const ushort* nLo = wn + 16384;

    int n0 = nb + frow;
    int n1 = nb + 16 + frow;
    bf16x8 B[4][2][2];
#pragma unroll
    for (int kt = 0; kt < 4; ++kt) {
        int k = kt * 32 + fk;
        B[kt][0][0] = *(const bf16x8*)(nHi + n0 * FEAT + k);
        B[kt][0][1] = *(const bf16x8*)(nLo + n0 * FEAT + k);
        B[kt][1][0] = *(const bf16x8*)(nHi + n1 * FEAT + k);
        B[kt][1][1] = *(const bf16x8*)(nLo + n1 * FEAT + k);
    }

    const int nTiles = (N_NODES + 127) / 128;  // 782
    int tile = blockIdx.x;

    {
        const char* hpg = (const char*)hb + (size_t)tile * 32768;
        char* sh = (char*)smem[0];
#pragma unroll
        for (int c = 0; c < 8; ++c) {
            int chunk = w * 8 + c;
            int d = chunk * 1024 + lane * 16;
            int s = d ^ (((d >> 8) & 7) << 4);
            GLOAD_LDS16(hpg + s, sh + chunk * 1024);
        }
    }
    __syncthreads();

    int buf = 0;
    int swz = (frow & 7) << 4;
    while (true) {
        int next = tile + CGRID;
        if (next < nTiles) {
            const char* hpg = (const char*)hb + (size_t)next * 32768;
            char* sh = (char*)smem[buf ^ 1];
#pragma unroll
            for (int c = 0; c < 8; ++c) {
                int chunk = w * 8 + c;
                int d = chunk * 1024 + lane * 16;
                int s = d ^ (((d >> 8) & 7) << 4);
                GLOAD_LDS16(hpg + s, sh + chunk * 1024);
            }
        }

        f32x4 acc[4][2];
#pragma unroll
        for (int mt = 0; mt < 4; ++mt)
#pragma unroll
            for (int nt = 0; nt < 2; ++nt) acc[mt][nt] = (f32x4)(0.f);

        {
            char* sh = (char*)smem[buf];
#pragma unroll
            for (int kt = 0; kt < 4; ++kt) {
                int kB = kt * 64 + fq * 16;
#pragma unroll
                for (int mt = 0; mt < 4; ++mt) {
                    int r = rh * 64 + mt * 16 + frow;
                    int off = ((r << 8) + kB) ^ swz;
                    bf16x8 Ah = *(const bf16x8*)(sh + off);
                    f32x4 c0 = acc[mt][0];
                    c0 = MFMA(Ah, B[kt][0][0], c0);
                    c0 = MFMA(Ah, B[kt][0][1], c0);
                    acc[mt][0] = c0;
                    f32x4 c1 = acc[mt][1];
                    c1 = MFMA(Ah, B[kt][1][0], c1);
                    c1 = MFMA(Ah, B[kt][1][1], c1);
                    acc[mt][1] = c1;
                }
            }
        }

        int v0 = tile * 128 + rh * 64;
#pragma unroll
        for (int nt = 0; nt < 2; ++nt) {
            int colo = nb + nt * 16 + (lane & 15);
            if (colo < 40) {
#pragma unroll
                for (int mt = 0; mt < 4; ++mt) {
#pragma unroll
                    for (int i = 0; i < 4; ++i) {
                        int v = v0 + mt * 16 + (lane >> 4) * 4 + i;
                        if (v >= N_NODES) continue;
                        pbuf[(size_t)v * 40 + colo] = f2bf(acc[mt][nt][i]);
                    }
                }
            }
        }

        if (next >= nTiles) break;
        __syncthreads();
        buf ^= 1;
        tile = next;
    }
}

__global__ __launch_bounds__(256) void agg4_kernel(const ushort* __restrict__ pbuf,
                                                   const int* __restrict__ row,
                                                   const int* __restrict__ col,
                                                   float* __restrict__ aggP) {
    int t = blockIdx.x * 256 + threadIdx.x;
    int v = t >> 5;
    int l = t & 31;
    if (v >= N_NODES || l >= 20) return;
    int beg = row[v], end = row[v + 1];
    const unsigned int* base = (const unsigned int*)pbuf;
    float s0 = 0.f, s1 = 0.f;
    int i = beg;
    for (; i + 4 <= end; i += 4) {
        int c0 = col[i], c1 = col[i + 1], c2 = col[i + 2], c3 = col[i + 3];
        unsigned int p0 = base[(size_t)c0 * 20 + l];
        unsigned int p1 = base[(size_t)c1 * 20 + l];
        unsigned int p2 = base[(size_t)c2 * 20 + l];
        unsigned int p3 = base[(size_t)c3 * 20 + l];
        s0 += lo16f(p0); s1 += hi16f(p0);
        s0 += lo16f(p1); s1 += hi16f(p1);
        s0 += lo16f(p2); s1 += hi16f(p2);
        s0 += lo16f(p3); s1 += hi16f(p3);
    }
    for (; i < end; ++i) {
        unsigned int p = base[(size_t)col[i] * 20 + l];
        s0 += lo16f(p); s1 += hi16f(p);
    }
    int deg = end - beg;
    float invd = 1.0f / (float)(deg > 0 ? deg : 1);
    float2 o; o.x = s0 * invd; o.y = s1 * invd;
    *(float2*)(aggP + (size_t)v * 40 + 2 * l) = o;
}

__global__ __launch_bounds__(256, 2) void combine4_kernel(
    const ushort* __restrict__ hb, const ushort* __restrict__ ws,
    const float* __restrict__ aggP, const float* __restrict__ bias,
    float* __restrict__ out) {
    __shared__ ushort smem[2][128 * FEAT];  // 2 x 32KB, swizzled hb tiles
    int tid = threadIdx.x;
    int lane = tid & 63;
    int w = tid >> 6;
    int rh = w >> 1;
    int nb = (w & 1) * 32;
    int frow = lane & 15;
    int fq = lane >> 4;
    int fk = fq * 8;
    const ushort* sHi = ws;
    const ushort* sLo = ws + 16384;

    int n0 = nb + frow;
    int n1 = nb + 16 + frow;
    bf16x8 B[4][2][2];
#pragma unroll
    for (int kt = 0; kt < 4; ++kt) {
        int k = kt * 32 + fk;
        B[kt][0][0] = *(const bf16x8*)(sHi + n0 * FEAT + k);
        B[kt][0][1] = *(const bf16x8*)(sLo + n0 * FEAT + k);
        B[kt][1][0] = *(const bf16x8*)(sHi + n1 * FEAT + k);
        B[kt][1][1] = *(const bf16x8*)(sLo + n1 * FEAT + k);
    }

    const int nTiles = (N_NODES + 127) / 128;  // 782
    int tile = blockIdx.x;

    {
        const char* hpg = (const char*)hb + (size_t)tile * 32768;
        char* sh = (char*)smem[0];
#pragma unroll
        for (int c = 0; c < 8; ++c) {
            int chunk = w * 8 + c;
            int d = chunk * 1024 + lane * 16;
            int s = d ^ (((d >> 8) & 7) << 4);
            GLOAD_LDS16(hpg + s, sh + chunk * 1024);
        }
    }
    __syncthreads();

    int buf = 0;
    int swz = (frow & 7) << 4;
    while (true) {
        int next = tile + CGRID;
        if (next < nTiles) {
            const char* hpg = (const char*)hb + (size_t)next * 32768;
            char* sh = (char*)smem[buf ^ 1];
#pragma unroll
            for (int c = 0; c < 8; ++c) {
                int chunk = w * 8 + c;
                int d = chunk * 1024 + lane * 16;
                int s = d ^ (((d >> 8) & 7) << 4);
                GLOAD_LDS16(hpg + s, sh + chunk * 1024);
            }
        }

        f32x4 acc[4][2];
#pragma unroll
        for (int mt = 0; mt < 4; ++mt)
#pragma unroll
            for (int nt = 0; nt < 2; ++nt) acc[mt][nt] = (f32x4)(0.f);

        {
            char* sh = (char*)smem[buf];
#pragma unroll
            for (int kt = 0; kt < 4; ++kt) {
                int kB = kt * 64 + fq * 16;
#pragma unroll
                for (int mt = 0; mt < 4; ++mt) {
                    int r = rh * 64 + mt * 16 + frow;
                    int off = ((r << 8) + kB) ^ swz;
                    bf16x8 Ah = *(const bf16x8*)(sh + off);
                    f32x4 c0 = acc[mt][0];
                    c0 = MFMA(Ah, B[kt][0][0], c0);
                    c0 = MFMA(Ah, B[kt][0][1], c0);
                    acc[mt][0] = c0;
                    f32x4 c1 = acc[mt][1];
                    c1 = MFMA(Ah, B[kt][1][0], c1);
                    c1 = MFMA(Ah, B[kt][1][1], c1);
                    acc[mt][1] = c1;
                }
            }
        }

        int v0 = tile * 128 + rh * 64;
#pragma unroll
        for (int nt = 0; nt < 2; ++nt) {
            int colo = nb + nt * 16 + (lane & 15);
            if (colo < 40) {
                float b = bias[colo];
#pragma unroll
                for (int mt = 0; mt < 4; ++mt) {
#pragma unroll
                    for (int i = 0; i < 4; ++i) {
                        int v = v0 + mt * 16 + (lane >> 4) * 4 + i;
                        if (v >= N_NODES) continue;
                        out[(size_t)v * 40 + colo] = acc[mt][nt][i] + b + aggP[(size_t)v * 40 + colo];
                    }
                }
            }
        }

        if (next >= nTiles) break;
        __syncthreads();
        buf ^= 1;
        tile = next;
    }
}

// ---------------- launch ----------------

static inline size_t align256(size_t x) { return (x + 255) & ~(size_t)255; }

extern "C" void kernel_launch(void* const* d_in, const int* in_sizes, int n_in,
                              void* d_out, int out_size, void* d_ws, size_t ws_size,
                              hipStream_t stream) {
    const float* x = (const float*)d_in[0];
    const int* src = (const int*)d_in[1];
    const int* dst = (const int*)d_in[2];
    const float* ws1 = (const float*)d_in[3];
    const float* wn1 = (const float*)d_in[4];
    const float* b1 = (const float*)d_in[5];
    const float* ws2 = (const float*)d_in[6];
    const float* wn2 = (const float*)d_in[7];
    const float* b2 = (const float*)d_in[8];
    const float* ws3 = (const float*)d_in[9];
    const float* wn3 = (const float*)d_in[10];
    const float* b3 = (const float*)d_in[11];
    const float* ws4 = (const float*)d_in[12];
    const float* wn4 = (const float*)d_in[13];
    const float* b4 = (const float*)d_in[14];
    float* out = (float*)d_out;

    char* base = (char*)d_ws;
    size_t off = 0;
    auto alloc = [&](size_t bytes) -> void* {
        void* p = base + off;
        off = align256(off + bytes);
        return p;
    };
    int* row = (int*)alloc((size_t)(N_NODES + 1) * 4);
    int* gcur = (int*)alloc((size_t)KB * 4);
    int* col = (int*)alloc((size_t)N_EDGES * 4);
    int2* pairs = (int2*)alloc((size_t)KB * BCAP * 8);   // 16.8 MB padded buckets
    ushort* wp = (ushort*)alloc((size_t)8 * 32768 * 2);
    ushort* xb = (ushort*)alloc((size_t)N_NODES * FEAT * 2);
    ushort* bufA = (ushort*)alloc((size_t)N_NODES * FEAT * 2);
    ushort* bufB = (ushort*)alloc((size_t)N_NODES * FEAT * 2);
    ushort* pbuf = (ushort*)alloc((size_t)N_NODES * 40 * 2);
    float* aggP = (float*)alloc((size_t)N_NODES * 40 * 4);
    (void)ws_size;

    // converts + CSR build
    hipMemsetAsync(gcur, 0, (size_t)KB * 4, stream);
    convert_x_kernel<<<(N_NODES * FEAT / 4 + 255) / 256, 256, 0, stream>>>(x, xb);
    convert_w_kernel<<<dim3(128, 8), 128, 0, stream>>>(ws1, wn1, ws2, wn2, ws3, wn3,
                                                       ws4, wn4, wp);
    fillA_kernel<<<(N_EDGES + TILE - 1) / TILE, 256, 0, stream>>>(src, dst, gcur, pairs);
    fillB_kernel<<<KB, 512, 0, stream>>>(pairs, gcur, row, col);

    const ushort* wp1 = wp;
    const ushort* wp2 = wp + (size_t)2 * 32768;
    const ushort* wp3 = wp + (size_t)4 * 32768;
    const ushort* wp4 = wp + (size_t)6 * 32768;

    int fgrid = N_NODES / 16;  // 6250, one-shot, 16 nodes per block

    // layers 1-3: fused gather-agg + MFMA tail
    fused_layer_kernel<<<fgrid, 1024, 0, stream>>>(xb, row, col, wp1, b1, bufA, 1);
    fused_layer_kernel<<<fgrid, 1024, 0, stream>>>(bufA, row, col, wp2, b2, bufB, 1);
    fused_layer_kernel<<<fgrid, 1024, 0, stream>>>(bufB, row, col, wp3, b3, bufA, 1);
    // layer 4: project -> aggregate(40-dim) -> self-combine
    proj_kernel<<<CGRID, 256, 0, stream>>>(bufA, wp4 + 32768, pbuf);
    agg4_kernel<<<((size_t)N_NODES * 32 + 255) / 256, 256, 0, stream>>>(pbuf, row, col, aggP);
    combine4_kernel<<<CGRID, 256, 0, stream>>>(bufA, wp4, aggP, b4, out);
}

// Round 11
// 488.120 us; speedup vs baseline: 1.3211x; 1.3211x over previous
//
#include <hip/hip_runtime.h>

#define N_NODES 100000
#define N_EDGES 1600000
#define FEAT 128
#define KB 256      // coarse buckets for edge partition (node ranges)
#define BCAP 8192   // padded capacity per bucket (mean 6250)
#define TILE 2048   // edges per fillA block
#define NPB 400     // max nodes per bucket (391) padded
#define CGRID 512   // persistent blocks (2 per CU)

typedef short bf16x8 __attribute__((ext_vector_type(8)));
typedef float f32x4 __attribute__((ext_vector_type(4)));

__device__ __forceinline__ ushort f2bf(float x) {
    union { float f; unsigned int u; } v; v.f = x;
    unsigned int u = v.u;
    return (ushort)((u + 0x7fffu + ((u >> 16) & 1u)) >> 16);  // RNE
}
__device__ __forceinline__ float bf2f(ushort h) {
    union { float f; unsigned int u; } v; v.u = ((unsigned int)h) << 16;
    return v.f;
}
__device__ __forceinline__ float lo16f(unsigned int u) {
    union { float f; unsigned int u; } v; v.u = u << 16;
    return v.f;
}
__device__ __forceinline__ float hi16f(unsigned int u) {
    union { float f; unsigned int u; } v; v.u = u & 0xffff0000u;
    return v.f;
}

#define MFMA(a, b, c) __builtin_amdgcn_mfma_f32_16x16x32_bf16((a), (b), (c), 0, 0, 0)

// async global->LDS, 16B per lane. dest = wave-uniform base + lane*16.
#define GLOAD_LDS16(g, l)                                                       \
    __builtin_amdgcn_global_load_lds(                                           \
        (const __attribute__((address_space(1))) unsigned int*)(g),             \
        (__attribute__((address_space(3))) unsigned int*)(l), 16, 0, 0)

// ---------------- CSR build ----------------

// fillA: per block, LDS count -> reserve run (1 global atomic/bucket) ->
// direct scatter into padded buckets. gcur zeroed by hipMemsetAsync.
__global__ __launch_bounds__(256) void fillA_kernel(const int* __restrict__ src,
                                                    const int* __restrict__ dst,
                                                    int* __restrict__ gcur,
                                                    int2* __restrict__ pairs) {
    __shared__ int cnt[KB];
    __shared__ int cur[KB];
    __shared__ int rbase[KB];
    int t = threadIdx.x;
    int base = blockIdx.x * TILE;
    cnt[t] = 0;
    __syncthreads();
    int myS[8], myD[8];
#pragma unroll
    for (int j = 0; j < 8; ++j) {
        int e = base + j * 256 + t;
        int s = 0, d = -1;
        if (e < N_EDGES) {
            s = src[e]; d = dst[e];
            int b = (int)(((unsigned)d * KB) / N_NODES);
            atomicAdd(&cnt[b], 1);
        }
        myS[j] = s; myD[j] = d;
    }
    __syncthreads();
    rbase[t] = atomicAdd(&gcur[t], cnt[t]);
    cur[t] = 0;
    __syncthreads();
#pragma unroll
    for (int j = 0; j < 8; ++j) {
        if (myD[j] >= 0) {
            int b = (int)(((unsigned)myD[j] * KB) / N_NODES);
            int slot = atomicAdd(&cur[b], 1);
            pairs[(size_t)b * BCAP + rbase[b] + slot] = make_int2(myS[j], myD[j]);
        }
    }
}

// fillB: one block per bucket; computes the global bucket prefix itself
// (folds the old bucket_base kernel), then local hist + scan -> row + col.
__global__ __launch_bounds__(512) void fillB_kernel(const int2* __restrict__ pairs,
                                                    const int* __restrict__ gcur,
                                                    int* __restrict__ row,
                                                    int* __restrict__ col) {
    __shared__ int ssrc[BCAP];      // 32 KB
    __shared__ ushort ld16[BCAP];   // 16 KB
    __shared__ int lcnt[NPB], lex[NPB], lcur[NPB];
    __shared__ int sc[512];
    __shared__ int pre[KB];
    int b = blockIdx.x;
    int t = threadIdx.x;
    int n0 = (b * N_NODES + KB - 1) / KB;
    int n1 = ((b + 1) * N_NODES + KB - 1) / KB;
    if (n1 > N_NODES) n1 = N_NODES;
    int nn = n1 - n0;
    int cnt = gcur[b];
    if (cnt > BCAP) cnt = BCAP;
    if (t < NPB) { lcnt[t] = 0; lcur[t] = 0; }
    // bucket prefix (inclusive scan over 256, replicated per block)
    if (t < KB) pre[t] = gcur[t];
    __syncthreads();
    for (int off = 1; off < KB; off <<= 1) {
        int x = 0, y = 0;
        if (t < KB) { x = pre[t]; y = (t >= off) ? pre[t - off] : 0; }
        __syncthreads();
        if (t < KB) pre[t] = x + y;
        __syncthreads();
    }
    int cbase = (b == 0) ? 0 : pre[b - 1];
    const int2* bp = pairs + (size_t)b * BCAP;
    for (int i = t; i < cnt; i += 512) {
        int2 pr = bp[i];
        int ld = pr.y - n0;
        atomicAdd(&lcnt[ld], 1);
        ld16[i] = (ushort)ld;
        ssrc[i] = pr.x;
    }
    __syncthreads();
    int val = (t < nn) ? lcnt[t] : 0;
    sc[t] = val;
    __syncthreads();
    for (int off = 1; off < 512; off <<= 1) {
        int x = sc[t];
        int y = (t >= off) ? sc[t - off] : 0;
        __syncthreads();
        sc[t] = x + y;
        __syncthreads();
    }
    if (t < nn) {
        int ex = sc[t] - val;
        lex[t] = ex;
        row[n0 + t] = cbase + ex;
    }
    if (b == 0 && t == 0) row[N_NODES] = N_EDGES;
    __syncthreads();
    for (int i = t; i < cnt; i += 512) {
        int ld = ld16[i];
        int pos = cbase + lex[ld] + atomicAdd(&lcur[ld], 1);
        col[pos] = ssrc[i];
    }
}

// ---------------- converts ----------------

__global__ __launch_bounds__(256) void convert_x_kernel(const float* __restrict__ x,
                                                        ushort* __restrict__ xb) {
    int idx = (blockIdx.x * 256 + threadIdx.x) * 4;
    if (idx >= N_NODES * FEAT) return;
    float4 v = *(const float4*)(x + idx);
    ushort4 o;
    o.x = f2bf(v.x); o.y = f2bf(v.y); o.z = f2bf(v.z); o.w = f2bf(v.w);
    *(ushort4*)(xb + idx) = o;
}

// weights fp32 -> (hi, lo) bf16 planes, zero-padded to 128 rows.
__global__ __launch_bounds__(128) void convert_w_kernel(
    const float* w0, const float* w1, const float* w2, const float* w3,
    const float* w4, const float* w5, const float* w6, const float* w7,
    ushort* __restrict__ wp) {
    int m = blockIdx.y;
    int r = blockIdx.x;
    int c = threadIdx.x;
    const float* src;
    switch (m) {
        case 0: src = w0; break; case 1: src = w1; break;
        case 2: src = w2; break; case 3: src = w3; break;
        case 4: src = w4; break; case 5: src = w5; break;
        case 6: src = w6; break; default: src = w7; break;
    }
    int rows = (m >= 6) ? 40 : 128;
    float val = (r < rows) ? src[r * FEAT + c] : 0.f;
    ushort hi = f2bf(val);
    ushort lo = f2bf(val - bf2f(hi));
    wp[(size_t)m * 32768 + r * FEAT + c] = hi;
    wp[(size_t)m * 32768 + 16384 + r * FEAT + c] = lo;
}

// ---------------- aggregation: dense, 16-edge pipelined unroll ----------------
// Frozen (r3: deeper ILP neutral; r4: working-set split regressed; r9/r10:
// both fusion forms regressed — v1 serialized nodes per wave, v2 added a
// per-block straggler barrier). The wall is the L2-miss fetch path:
// 178MB at 3.6TB/s ~= 49us of the 57us. Independent 4-wave blocks with
// one node per wave is the proven concurrency shape.

__global__ __launch_bounds__(256) void agg_kernel(const ushort* __restrict__ hb,
                                                  const int* __restrict__ row,
                                                  const int* __restrict__ col,
                                                  ushort* __restrict__ aggB) {
    int t = blockIdx.x * 256 + threadIdx.x;
    int v = t >> 6;
    int lane = t & 63;
    if (v >= N_NODES) return;
    int g = lane >> 4;
    int flOff = (lane & 15) * 16;  // byte offset of this lane's 16B chunk
    int beg = row[v], end = row[v + 1];
    int deg = end - beg;
    float a0 = 0.f, a1 = 0.f, a2 = 0.f, a3 = 0.f;
    float a4 = 0.f, a5 = 0.f, a6 = 0.f, a7 = 0.f;
    const char* hp = (const char*)hb;

#define ACC8(p)                                          \
    a0 += lo16f((p).x); a1 += hi16f((p).x);              \
    a2 += lo16f((p).y); a3 += hi16f((p).y);              \
    a4 += lo16f((p).z); a5 += hi16f((p).z);              \
    a6 += lo16f((p).w); a7 += hi16f((p).w);

    int i = beg;
    int end16 = beg + (deg & ~15);
    if (i < end16) {
        int c0 = col[i + g];
        int c1 = col[i + 4 + g];
        int c2 = col[i + 8 + g];
        int c3 = col[i + 12 + g];
        while (true) {
            uint4 p0 = *(const uint4*)(hp + (((unsigned)c0 << 8) | (unsigned)flOff));
            uint4 p1 = *(const uint4*)(hp + (((unsigned)c1 << 8) | (unsigned)flOff));
            uint4 p2 = *(const uint4*)(hp + (((unsigned)c2 << 8) | (unsigned)flOff));
            uint4 p3 = *(const uint4*)(hp + (((unsigned)c3 << 8) | (unsigned)flOff));
            i += 16;
            bool more = i < end16;
            if (more) {
                c0 = col[i + g];
                c1 = col[i + 4 + g];
                c2 = col[i + 8 + g];
                c3 = col[i + 12 + g];
            }
            ACC8(p0);
            ACC8(p1);
            ACC8(p2);
            ACC8(p3);
            if (!more) break;
        }
    }
    if (i + 8 <= end) {
        int c0 = col[i + g];
        int c1 = col[i + 4 + g];
        uint4 p0 = *(const uint4*)(hp + (((unsigned)c0 << 8) | (unsigned)flOff));
        uint4 p1 = *(const uint4*)(hp + (((unsigned)c1 << 8) | (unsigned)flOff));
        ACC8(p0);
        ACC8(p1);
        i += 8;
    }
    if (i + 4 <= end) {
        int c = col[i + g];
        uint4 p = *(const uint4*)(hp + (((unsigned)c << 8) | (unsigned)flOff));
        ACC8(p);
        i += 4;
    }
    if (i < end) {
        int e = i + g;
        bool ok = e < end;
        int c = col[ok ? e : beg];
        uint4 p = *(const uint4*)(hp + (((unsigned)c << 8) | (unsigned)flOff));
        float m = ok ? 1.f : 0.f;
        a0 += m * lo16f(p.x); a1 += m * hi16f(p.x);
        a2 += m * lo16f(p.y); a3 += m * hi16f(p.y);
        a4 += m * lo16f(p.z); a5 += m * hi16f(p.z);
        a6 += m * lo16f(p.w); a7 += m * hi16f(p.w);
    }
#undef ACC8

    // reduce across edge slots (lanes fl, fl+16, fl+32, fl+48)
    a0 += __shfl_xor(a0, 16); a1 += __shfl_xor(a1, 16);
    a2 += __shfl_xor(a2, 16); a3 += __shfl_xor(a3, 16);
    a4 += __shfl_xor(a4, 16); a5 += __shfl_xor(a5, 16);
    a6 += __shfl_xor(a6, 16); a7 += __shfl_xor(a7, 16);
    a0 += __shfl_xor(a0, 32); a1 += __shfl_xor(a1, 32);
    a2 += __shfl_xor(a2, 32); a3 += __shfl_xor(a3, 32);
    a4 += __shfl_xor(a4, 32); a5 += __shfl_xor(a5, 32);
    a6 += __shfl_xor(a6, 32); a7 += __shfl_xor(a7, 32);
    if (g == 0) {
        float invd = 1.0f / (float)(deg > 0 ? deg : 1);
        uint4 o;
        o.x = (unsigned)f2bf(a0 * invd) | ((unsigned)f2bf(a1 * invd) << 16);
        o.y = (unsigned)f2bf(a2 * invd) | ((unsigned)f2bf(a3 * invd) << 16);
        o.z = (unsigned)f2bf(a4 * invd) | ((unsigned)f2bf(a5 * invd) << 16);
        o.w = (unsigned)f2bf(a6 * invd) | ((unsigned)f2bf(a7 * invd) << 16);
        *(uint4*)((char*)aggB + (((size_t)v << 8) | (unsigned)flOff)) = o;
    }
}

// ---------------- combine (layers 1-3): persistent double-buffered pipeline ----------------
// r6's best-measured configuration (64-row tiles, CGRID 512, 2 blocks/CU):
// part of the 493.2us total. r7's 32-row/(256,4) spilled (VGPR cliff); r8's
// 32-row/(256,2) was neutral-to-slightly-worse (497.2). Reverted to r6.

__global__ __launch_bounds__(256, 2) void combine_kernel(
    const ushort* __restrict__ hb, const ushort* __restrict__ aggB,
    const ushort* __restrict__ wp,   // [sHi|sLo|nHi|nLo] planes
    const float* __restrict__ bias,
    ushort* __restrict__ outB, int doRelu) {
    __shared__ ushort smemH[2][64 * FEAT];  // 2 x 16KB, swizzled hb tiles
    __shared__ ushort smemA[2][64 * FEAT];  // 2 x 16KB, swizzled aggB tiles
    int tid = threadIdx.x;
    int lane = tid & 63;
    int w = tid >> 6;
    int frow = lane & 15;
    int fq = lane >> 4;
    int fk = fq * 8;
    int nb = w * 32;

    const ushort* sHi = wp;
    const ushort* sLo = wp + 16384;
    const ushort* nHi = wp + 32768;
    const ushort* nLo = wp + 49152;

    // ---- B into registers ONCE: 32 x bf16x8 (128 VGPRs; total 116 measured) ----
    int n0 = nb + frow;
    int n1 = nb + 16 + frow;
    bf16x8 B[4][2][4];
#pragma unroll
    for (int kt = 0; kt < 4; ++kt) {
        int k = kt * 32 + fk;
        B[kt][0][0] = *(const bf16x8*)(sHi + n0 * FEAT + k);
        B[kt][0][1] = *(const bf16x8*)(sLo + n0 * FEAT + k);
        B[kt][0][2] = *(const bf16x8*)(nHi + n0 * FEAT + k);
        B[kt][0][3] = *(const bf16x8*)(nLo + n0 * FEAT + k);
        B[kt][1][0] = *(const bf16x8*)(sHi + n1 * FEAT + k);
        B[kt][1][1] = *(const bf16x8*)(sLo + n1 * FEAT + k);
        B[kt][1][2] = *(const bf16x8*)(nHi + n1 * FEAT + k);
        B[kt][1][3] = *(const bf16x8*)(nLo + n1 * FEAT + k);
    }

    const int nTiles = (N_NODES + 63) / 64;  // 1563
    int tile = blockIdx.x;

    // ---- prologue: stage tile into buf 0 ----
    {
        const char* hpg = (const char*)hb + (size_t)tile * 16384;
        const char* apg = (const char*)aggB + (size_t)tile * 16384;
        char* shH = (char*)smemH[0];
        char* shA = (char*)smemA[0];
#pragma unroll
        for (int c = 0; c < 4; ++c) {
            int chunk = w * 4 + c;
            int d = chunk * 1024 + lane * 16;
            int s = d ^ (((d >> 8) & 7) << 4);  // involution: LDS[x^swz] = G[x]
            GLOAD_LDS16(hpg + s, shH + chunk * 1024);
            GLOAD_LDS16(apg + s, shA + chunk * 1024);
        }
    }
    __syncthreads();  // drains vmcnt(0): prologue DMA + B loads complete

    int buf = 0;
    int swz = (frow & 7) << 4;
    while (true) {
        int next = tile + CGRID;
        // ---- issue next tile's DMA into the other buffer ----
        if (next < nTiles) {
            const char* hpg = (const char*)hb + (size_t)next * 16384;
            const char* apg = (const char*)aggB + (size_t)next * 16384;
            char* shH = (char*)smemH[buf ^ 1];
            char* shA = (char*)smemA[buf ^ 1];
#pragma unroll
            for (int c = 0; c < 4; ++c) {
                int chunk = w * 4 + c;
                int d = chunk * 1024 + lane * 16;
                int s = d ^ (((d >> 8) & 7) << 4);
                GLOAD_LDS16(hpg + s, shH + chunk * 1024);
                GLOAD_LDS16(apg + s, shA + chunk * 1024);
            }
        }

        // ---- compute current tile from smem[buf] ----
        f32x4 acc[4][2];
#pragma unroll
        for (int mt = 0; mt < 4; ++mt)
#pragma unroll
            for (int nt = 0; nt < 2; ++nt) acc[mt][nt] = (f32x4)(0.f);

        {
            char* shH = (char*)smemH[buf];
            char* shA = (char*)smemA[buf];
#pragma unroll
            for (int kt = 0; kt < 4; ++kt) {
                int kB = kt * 64 + fq * 16;  // byte offset of this lane's k-chunk
#pragma unroll
                for (int mt = 0; mt < 4; ++mt) {
                    int off = (((mt * 16 + frow) << 8) + kB) ^ swz;
                    bf16x8 Ah = *(const bf16x8*)(shH + off);
                    bf16x8 Aa = *(const bf16x8*)(shA + off);
#pragma unroll
                    for (int nt = 0; nt < 2; ++nt) {
                        f32x4 c = acc[mt][nt];
                        c = MFMA(Ah, B[kt][nt][0], c);
                        c = MFMA(Ah, B[kt][nt][1], c);
                        c = MFMA(Aa, B[kt][nt][2], c);
                        c = MFMA(Aa, B[kt][nt][3], c);
                        acc[mt][nt] = c;
                    }
                }
            }
        }

        // ---- epilogue for current tile ----
        int v0 = tile * 64;
#pragma unroll
        for (int nt = 0; nt < 2; ++nt) {
            int colo = nb + nt * 16 + (lane & 15);
            float b = bias[colo];
#pragma unroll
            for (int mt = 0; mt < 4; ++mt) {
#pragma unroll
                for (int i = 0; i < 4; ++i) {
                    int v = v0 + mt * 16 + (lane >> 4) * 4 + i;
                    if (v >= N_NODES) continue;
                    float r = acc[mt][nt][i] + b;
                    if (doRelu) r = fmaxf(r, 0.f);
                    outB[(size_t)v * FEAT + colo] = f2bf(r);
                }
            }
        }

        if (next >= nTiles) break;
        __syncthreads();  // next-tile DMA landed; smem[buf] free for re-stage
        buf ^= 1;
        tile = next;
    }
}

// ---------------- layer 4: persistent project-then-aggregate ----------------

__global__ __launch_bounds__(256, 2) void proj_kernel(
    const ushort* __restrict__ hb, const ushort* __restrict__ wn,
    ushort* __restrict__ pbuf) {
    __shared__ ushort smem[2][128 * FEAT];  // 2 x 32KB, swizzled hb tiles
    int tid = threadIdx.x;
    int lane = tid & 63;
    int w = tid >> 6;
    int rh = w >> 1;          // row-half (0: rows 0-63, 1: rows 64-127)
    int nb = (w & 1) * 32;    // col-half of the 64 weight rows
    int frow = lane & 15;
    int fq = lane >> 4;
    int fk = fq * 8;
    const ushort* nHi = wn;
    const ushort* nLo = wn + 16384;

    int n0 = nb + frow;
    int n1 = nb + 16 + frow;
    bf16x8 B[4][2][2];
#pragma unroll
    for (int kt = 0; kt < 4; ++kt) {
        int k = kt * 32 + fk;
        B[kt][0][0] = *(const bf16x8*)(nHi + n0 * FEAT + k);
        B[kt][0][1] = *(const bf16x8*)(nLo + n0 * FEAT + k);
        B[kt][1][0] = *(const bf16x8*)(nHi + n1 * FEAT + k);
        B[kt][1][1] = *(const bf16x8*)(nLo + n1 * FEAT + k);
    }

    const int nTiles = (N_NODES + 127) / 128;  // 782
    int tile = blockIdx.x;

    {
        const char* hpg = (const char*)hb + (size_t)tile * 32768;
        char* sh = (char*)smem[0];
#pragma unroll
        for (int c = 0; c < 8; ++c) {
            int chunk = w * 8 + c;
            int d = chunk * 1024 + lane * 16;
            int s = d ^ (((d >> 8) & 7) << 4);
            GLOAD_LDS16(hpg + s, sh + chunk * 1024);
        }
    }
    __syncthreads();

    int buf = 0;
    int swz = (frow & 7) << 4;
    while (true) {
        int next = tile + CGRID;
        if (next < nTiles) {
            const char* hpg = (const char*)hb + (size_t)next * 32768;
            char* sh = (char*)smem[buf ^ 1];
#pragma unroll
            for (int c = 0; c < 8; ++c) {
                int chunk = w * 8 + c;
                int d = chunk * 1024 + lane * 16;
                int s = d ^ (((d >> 8) & 7) << 4);
                GLOAD_LDS16(hpg + s, sh + chunk * 1024);
            }
        }

        f32x4 acc[4][2];
#pragma unroll
        for (int mt = 0; mt < 4; ++mt)
#pragma unroll
            for (int nt = 0; nt < 2; ++nt) acc[mt][nt] = (f32x4)(0.f);

        {
            char* sh = (char*)smem[buf];
#pragma unroll
            for (int kt = 0; kt < 4; ++kt) {
                int kB = kt * 64 + fq * 16;
#pragma unroll
                for (int mt = 0; mt < 4; ++mt) {
                    int r = rh * 64 + mt * 16 + frow;
                    int off = ((r << 8) + kB) ^ swz;
                    bf16x8 Ah = *(const bf16x8*)(sh + off);
                    f32x4 c0 = acc[mt][0];
                    c0 = MFMA(Ah, B[kt][0][0], c0);
                    c0 = MFMA(Ah, B[kt][0][1], c0);
                    acc[mt][0] = c0;
                    f32x4 c1 = acc[mt][1];
                    c1 = MFMA(Ah, B[kt][1][0], c1);
                    c1 = MFMA(Ah, B[kt][1][1], c1);
                    acc[mt][1] = c1;
                }
            }
        }

        int v0 = tile * 128 + rh * 64;
#pragma unroll
        for (int nt = 0; nt < 2; ++nt) {
            int colo = nb + nt * 16 + (lane & 15);
            if (colo < 40) {
#pragma unroll
                for (int mt = 0; mt < 4; ++mt) {
#pragma unroll
                    for (int i = 0; i < 4; ++i) {
                        int v = v0 + mt * 16 + (lane >> 4) * 4 + i;
                        if (v >= N_NODES) continue;
                        pbuf[(size_t)v * 40 + colo] = f2bf(acc[mt][nt][i]);
                    }
                }
            }
        }

        if (next >= nTiles) break;
        __syncthreads();
        buf ^= 1;
        tile = next;
    }
}

__global__ __launch_bounds__(256) void agg4_kernel(const ushort* __restrict__ pbuf,
                                                   const int* __restrict__ row,
                                                   const int* __restrict__ col,
                                                   float* __restrict__ aggP) {
    int t = blockIdx.x * 256 + threadIdx.x;
    int v = t >> 5;
    int l = t & 31;
    if (v >= N_NODES || l >= 20) return;
    int beg = row[v], end = row[v + 1];
    const unsigned int* base = (const unsigned int*)pbuf;
    float s0 = 0.f, s1 = 0.f;
    int i = beg;
    for (; i + 4 <= end; i += 4) {
        int c0 = col[i], c1 = col[i + 1], c2 = col[i + 2], c3 = col[i + 3];
        unsigned int p0 = base[(size_t)c0 * 20 + l];
        unsigned int p1 = base[(size_t)c1 * 20 + l];
        unsigned int p2 = base[(size_t)c2 * 20 + l];
        unsigned int p3 = base[(size_t)c3 * 20 + l];
        s0 += lo16f(p0); s1 += hi16f(p0);
        s0 += lo16f(p1); s1 += hi16f(p1);
        s0 += lo16f(p2); s1 += hi16f(p2);
        s0 += lo16f(p3); s1 += hi16f(p3);
    }
    for (; i < end; ++i) {
        unsigned int p = base[(size_t)col[i] * 20 + l];
        s0 += lo16f(p); s1 += hi16f(p);
    }
    int deg = end - beg;
    float invd = 1.0f / (float)(deg > 0 ? deg : 1);
    float2 o; o.x = s0 * invd; o.y = s1 * invd;
    *(float2*)(aggP + (size_t)v * 40 + 2 * l) = o;
}

__global__ __launch_bounds__(256, 2) void combine4_kernel(
    const ushort* __restrict__ hb, const ushort* __restrict__ ws,
    const float* __restrict__ aggP, const float* __restrict__ bias,
    float* __restrict__ out) {
    __shared__ ushort smem[2][128 * FEAT];  // 2 x 32KB, swizzled hb tiles
    int tid = threadIdx.x;
    int lane = tid & 63;
    int w = tid >> 6;
    int rh = w >> 1;
    int nb = (w & 1) * 32;
    int frow = lane & 15;
    int fq = lane >> 4;
    int fk = fq * 8;
    const ushort* sHi = ws;
    const ushort* sLo = ws + 16384;

    int n0 = nb + frow;
    int n1 = nb + 16 + frow;
    bf16x8 B[4][2][2];
#pragma unroll
    for (int kt = 0; kt < 4; ++kt) {
        int k = kt * 32 + fk;
        B[kt][0][0] = *(const bf16x8*)(sHi + n0 * FEAT + k);
        B[kt][0][1] = *(const bf16x8*)(sLo + n0 * FEAT + k);
        B[kt][1][0] = *(const bf16x8*)(sHi + n1 * FEAT + k);
        B[kt][1][1] = *(const bf16x8*)(sLo + n1 * FEAT + k);
    }

    const int nTiles = (N_NODES + 127) / 128;  // 782
    int tile = blockIdx.x;

    {
        const char* hpg = (const char*)hb + (size_t)tile * 32768;
        char* sh = (char*)smem[0];
#pragma unroll
        for (int c = 0; c < 8; ++c) {
            int chunk = w * 8 + c;
            int d = chunk * 1024 + lane * 16;
            int s = d ^ (((d >> 8) & 7) << 4);
            GLOAD_LDS16(hpg + s, sh + chunk * 1024);
        }
    }
    __syncthreads();

    int buf = 0;
    int swz = (frow & 7) << 4;
    while (true) {
        int next = tile + CGRID;
        if (next < nTiles) {
            const char* hpg = (const char*)hb + (size_t)next * 32768;
            char* sh = (char*)smem[buf ^ 1];
#pragma unroll
            for (int c = 0; c < 8; ++c) {
                int chunk = w * 8 + c;
                int d = chunk * 1024 + lane * 16;
                int s = d ^ (((d >> 8) & 7) << 4);
                GLOAD_LDS16(hpg + s, sh + chunk * 1024);
            }
        }

        f32x4 acc[4][2];
#pragma unroll
        for (int mt = 0; mt < 4; ++mt)
#pragma unroll
            for (int nt = 0; nt < 2; ++nt) acc[mt][nt] = (f32x4)(0.f);

        {
            char* sh = (char*)smem[buf];
#pragma unroll
            for (int kt = 0; kt < 4; ++kt) {
                int kB = kt * 64 + fq * 16;
#pragma unroll
                for (int mt = 0; mt < 4; ++mt) {
                    int r = rh * 64 + mt * 16 + frow;
                    int off = ((r << 8) + kB) ^ swz;
                    bf16x8 Ah = *(const bf16x8*)(sh + off);
                    f32x4 c0 = acc[mt][0];
                    c0 = MFMA(Ah, B[kt][0][0], c0);
                    c0 = MFMA(Ah, B[kt][0][1], c0);
                    acc[mt][0] = c0;
                    f32x4 c1 = acc[mt][1];
                    c1 = MFMA(Ah, B[kt][1][0], c1);
                    c1 = MFMA(Ah, B[kt][1][1], c1);
                    acc[mt][1] = c1;
                }
            }
        }

        int v0 = tile * 128 + rh * 64;
#pragma unroll
        for (int nt = 0; nt < 2; ++nt) {
            int colo = nb + nt * 16 + (lane & 15);
            if (colo < 40) {
                float b = bias[colo];
#pragma unroll
                for (int mt = 0; mt < 4; ++mt) {
#pragma unroll
                    for (int i = 0; i < 4; ++i) {
                        int v = v0 + mt * 16 + (lane >> 4) * 4 + i;
                        if (v >= N_NODES) continue;
                        out[(size_t)v * 40 + colo] = acc[mt][nt][i] + b + aggP[(size_t)v * 40 + colo];
                    }
                }
            }
        }

        if (next >= nTiles) break;
        __syncthreads();
        buf ^= 1;
        tile = next;
    }
}

// ---------------- launch ----------------

static inline size_t align256(size_t x) { return (x + 255) & ~(size_t)255; }

extern "C" void kernel_launch(void* const* d_in, const int* in_sizes, int n_in,
                              void* d_out, int out_size, void* d_ws, size_t ws_size,
                              hipStream_t stream) {
    const float* x = (const float*)d_in[0];
    const int* src = (const int*)d_in[1];
    const int* dst = (const int*)d_in[2];
    const float* ws1 = (const float*)d_in[3];
    const float* wn1 = (const float*)d_in[4];
    const float* b1 = (const float*)d_in[5];
    const float* ws2 = (const float*)d_in[6];
    const float* wn2 = (const float*)d_in[7];
    const float* b2 = (const float*)d_in[8];
    const float* ws3 = (const float*)d_in[9];
    const float* wn3 = (const float*)d_in[10];
    const float* b3 = (const float*)d_in[11];
    const float* ws4 = (const float*)d_in[12];
    const float* wn4 = (const float*)d_in[13];
    const float* b4 = (const float*)d_in[14];
    float* out = (float*)d_out;

    char* base = (char*)d_ws;
    size_t off = 0;
    auto alloc = [&](size_t bytes) -> void* {
        void* p = base + off;
        off = align256(off + bytes);
        return p;
    };
    int* row = (int*)alloc((size_t)(N_NODES + 1) * 4);
    int* gcur = (int*)alloc((size_t)KB * 4);
    int* col = (int*)alloc((size_t)N_EDGES * 4);
    int2* pairs = (int2*)alloc((size_t)KB * BCAP * 8);   // 16.8 MB padded buckets
    ushort* wp = (ushort*)alloc((size_t)8 * 32768 * 2);
    ushort* xb = (ushort*)alloc((size_t)N_NODES * FEAT * 2);
    ushort* bufA = (ushort*)alloc((size_t)N_NODES * FEAT * 2);
    ushort* bufB = (ushort*)alloc((size_t)N_NODES * FEAT * 2);
    ushort* aggB = (ushort*)alloc((size_t)N_NODES * FEAT * 2);
    ushort* pbuf = (ushort*)alloc((size_t)N_NODES * 40 * 2);
    float* aggP = (float*)alloc((size_t)N_NODES * 40 * 4);
    (void)ws_size;

    // converts + CSR build
    hipMemsetAsync(gcur, 0, (size_t)KB * 4, stream);
    convert_x_kernel<<<(N_NODES * FEAT / 4 + 255) / 256, 256, 0, stream>>>(x, xb);
    convert_w_kernel<<<dim3(128, 8), 128, 0, stream>>>(ws1, wn1, ws2, wn2, ws3, wn3,
                                                       ws4, wn4, wp);
    fillA_kernel<<<(N_EDGES + TILE - 1) / TILE, 256, 0, stream>>>(src, dst, gcur, pairs);
    fillB_kernel<<<KB, 512, 0, stream>>>(pairs, gcur, row, col);

    int aggGrid = ((size_t)N_NODES * 64 + 255) / 256;   // 25000

    const ushort* wp1 = wp;
    const ushort* wp2 = wp + (size_t)2 * 32768;
    const ushort* wp3 = wp + (size_t)4 * 32768;
    const ushort* wp4 = wp + (size_t)6 * 32768;

    agg_kernel<<<aggGrid, 256, 0, stream>>>(xb, row, col, aggB);
    combine_kernel<<<CGRID, 256, 0, stream>>>(xb, aggB, wp1, b1, bufA, 1);
    agg_kernel<<<aggGrid, 256, 0, stream>>>(bufA, row, col, aggB);
    combine_kernel<<<CGRID, 256, 0, stream>>>(bufA, aggB, wp2, b2, bufB, 1);
    agg_kernel<<<aggGrid, 256, 0, stream>>>(bufB, row, col, aggB);
    combine_kernel<<<CGRID, 256, 0, stream>>>(bufB, aggB, wp3, b3, bufA, 1);
    // layer 4: project -> aggregate(40-dim) -> self-combine
    proj_kernel<<<CGRID, 256, 0, stream>>>(bufA, wp4 + 32768, pbuf);
    agg4_kernel<<<((size_t)N_NODES * 32 + 255) / 256, 256, 0, stream>>>(pbuf, row, col, aggP);
    combine4_kernel<<<CGRID, 256, 0, stream>>>(bufA, wp4, aggP, b4, out);
}

// Round 12
// 473.653 us; speedup vs baseline: 1.3615x; 1.0305x over previous
//
#include <hip/hip_runtime.h>

#define N_NODES 100000
#define N_EDGES 1600000
#define FEAT 128
#define KB 256      // coarse buckets for edge partition (node ranges)
#define BCAP 8192   // padded capacity per bucket (mean 6250)
#define TILE 2048   // edges per fillA block
#define NPB 400     // max nodes per bucket (391) padded
#define CGRID 512   // persistent blocks (2 per CU)

#define ABLKS ((N_EDGES + TILE - 1) / TILE)   // 782  fillA blocks
#define XBLKS 12500                           // convert_x blocks (exact)
#define WBLKS 512                             // convert_w blocks (8 mat x 64)

typedef short bf16x8 __attribute__((ext_vector_type(8)));
typedef float f32x4 __attribute__((ext_vector_type(4)));

__device__ __forceinline__ ushort f2bf(float x) {
    union { float f; unsigned int u; } v; v.f = x;
    unsigned int u = v.u;
    return (ushort)((u + 0x7fffu + ((u >> 16) & 1u)) >> 16);  // RNE
}
__device__ __forceinline__ float bf2f(ushort h) {
    union { float f; unsigned int u; } v; v.u = ((unsigned int)h) << 16;
    return v.f;
}
__device__ __forceinline__ float lo16f(unsigned int u) {
    union { float f; unsigned int u; } v; v.u = u << 16;
    return v.f;
}
__device__ __forceinline__ float hi16f(unsigned int u) {
    union { float f; unsigned int u; } v; v.u = u & 0xffff0000u;
    return v.f;
}

#define MFMA(a, b, c) __builtin_amdgcn_mfma_f32_16x16x32_bf16((a), (b), (c), 0, 0, 0)

// async global->LDS, 16B per lane. dest = wave-uniform base + lane*16.
#define GLOAD_LDS16(g, l)                                                       \
    __builtin_amdgcn_global_load_lds(                                           \
        (const __attribute__((address_space(1))) unsigned int*)(g),             \
        (__attribute__((address_space(3))) unsigned int*)(l), 16, 0, 0)

// ---------------- frontend: convert_x + convert_w + fillA in ONE dispatch ----------------
// r11 ledger: ~229us of unprofiled remainder across 8 small dispatches. These
// three are mutually independent (gcur zeroed by the preceding same-stream
// memset), so a blockIdx-range merge turns sum-of-three into max-of-three.
// Block order: fillA first (fillB's dependency), then convert_x, convert_w.

__global__ __launch_bounds__(256) void frontend_kernel(
    const float* __restrict__ x, ushort* __restrict__ xb,
    const float* w0, const float* w1, const float* w2, const float* w3,
    const float* w4, const float* w5, const float* w6, const float* w7,
    ushort* __restrict__ wp,
    const int* __restrict__ src, const int* __restrict__ dst,
    int* __restrict__ gcur, int2* __restrict__ pairs) {
    __shared__ int cnt[KB];
    __shared__ int cur[KB];
    __shared__ int rbase[KB];
    int b = blockIdx.x;
    int t = threadIdx.x;

    if (b < ABLKS) {
        // ---- fillA: LDS count -> reserve run -> direct scatter ----
        int base = b * TILE;
        cnt[t] = 0;
        __syncthreads();
        int myS[8], myD[8];
#pragma unroll
        for (int j = 0; j < 8; ++j) {
            int e = base + j * 256 + t;
            int s = 0, d = -1;
            if (e < N_EDGES) {
                s = src[e]; d = dst[e];
                int bk = (int)(((unsigned)d * KB) / N_NODES);
                atomicAdd(&cnt[bk], 1);
            }
            myS[j] = s; myD[j] = d;
        }
        __syncthreads();
        rbase[t] = atomicAdd(&gcur[t], cnt[t]);
        cur[t] = 0;
        __syncthreads();
#pragma unroll
        for (int j = 0; j < 8; ++j) {
            if (myD[j] >= 0) {
                int bk = (int)(((unsigned)myD[j] * KB) / N_NODES);
                int slot = atomicAdd(&cur[bk], 1);
                pairs[(size_t)bk * BCAP + rbase[bk] + slot] = make_int2(myS[j], myD[j]);
            }
        }
    } else if (b < ABLKS + XBLKS) {
        // ---- convert_x: fp32 -> bf16, float4 vectorized ----
        int idx = ((b - ABLKS) * 256 + t) * 4;
        float4 v = *(const float4*)(x + idx);
        ushort4 o;
        o.x = f2bf(v.x); o.y = f2bf(v.y); o.z = f2bf(v.z); o.w = f2bf(v.w);
        *(ushort4*)(xb + idx) = o;
    } else {
        // ---- convert_w: fp32 -> (hi,lo) bf16 planes, 2 rows per block ----
        int wblk = b - ABLKS - XBLKS;
        int m = wblk >> 6;
        int r = ((wblk & 63) << 1) | (t >> 7);
        int c = t & 127;
        const float* srcw;
        switch (m) {
            case 0: srcw = w0; break; case 1: srcw = w1; break;
            case 2: srcw = w2; break; case 3: srcw = w3; break;
            case 4: srcw = w4; break; case 5: srcw = w5; break;
            case 6: srcw = w6; break; default: srcw = w7; break;
        }
        int rows = (m >= 6) ? 40 : 128;
        float val = (r < rows) ? srcw[r * FEAT + c] : 0.f;
        ushort hi = f2bf(val);
        ushort lo = f2bf(val - bf2f(hi));
        wp[(size_t)m * 32768 + r * FEAT + c] = hi;
        wp[(size_t)m * 32768 + 16384 + r * FEAT + c] = lo;
    }
}

// fillB: one block per bucket; computes the global bucket prefix itself,
// then local hist + scan -> row + col.
__global__ __launch_bounds__(512) void fillB_kernel(const int2* __restrict__ pairs,
                                                    const int* __restrict__ gcur,
                                                    int* __restrict__ row,
                                                    int* __restrict__ col) {
    __shared__ int ssrc[BCAP];      // 32 KB
    __shared__ ushort ld16[BCAP];   // 16 KB
    __shared__ int lcnt[NPB], lex[NPB], lcur[NPB];
    __shared__ int sc[512];
    __shared__ int pre[KB];
    int b = blockIdx.x;
    int t = threadIdx.x;
    int n0 = (b * N_NODES + KB - 1) / KB;
    int n1 = ((b + 1) * N_NODES + KB - 1) / KB;
    if (n1 > N_NODES) n1 = N_NODES;
    int nn = n1 - n0;
    int cnt = gcur[b];
    if (cnt > BCAP) cnt = BCAP;
    if (t < NPB) { lcnt[t] = 0; lcur[t] = 0; }
    // bucket prefix (inclusive scan over 256, replicated per block)
    if (t < KB) pre[t] = gcur[t];
    __syncthreads();
    for (int off = 1; off < KB; off <<= 1) {
        int x = 0, y = 0;
        if (t < KB) { x = pre[t]; y = (t >= off) ? pre[t - off] : 0; }
        __syncthreads();
        if (t < KB) pre[t] = x + y;
        __syncthreads();
    }
    int cbase = (b == 0) ? 0 : pre[b - 1];
    const int2* bp = pairs + (size_t)b * BCAP;
    for (int i = t; i < cnt; i += 512) {
        int2 pr = bp[i];
        int ld = pr.y - n0;
        atomicAdd(&lcnt[ld], 1);
        ld16[i] = (ushort)ld;
        ssrc[i] = pr.x;
    }
    __syncthreads();
    int val = (t < nn) ? lcnt[t] : 0;
    sc[t] = val;
    __syncthreads();
    for (int off = 1; off < 512; off <<= 1) {
        int x = sc[t];
        int y = (t >= off) ? sc[t - off] : 0;
        __syncthreads();
        sc[t] = x + y;
        __syncthreads();
    }
    if (t < nn) {
        int ex = sc[t] - val;
        lex[t] = ex;
        row[n0 + t] = cbase + ex;
    }
    if (b == 0 && t == 0) row[N_NODES] = N_EDGES;
    __syncthreads();
    for (int i = t; i < cnt; i += 512) {
        int ld = ld16[i];
        int pos = cbase + lex[ld] + atomicAdd(&lcur[ld], 1);
        col[pos] = ssrc[i];
    }
}

// ---------------- aggregation: dense, 16-edge pipelined unroll ----------------
// Frozen (r3: deeper ILP neutral; r4: working-set split regressed; r9/r10:
// both fusion forms regressed). Sharpened model (r11): static throughputs
// (VALU 2.6us, TA 2.6us, L2 12us, miss path 12-15us) all far below the 57us
// measured; with ILP and TLP levers both falsified, the binding constraint
// is per-CU L1 miss-queue depth x L2 latency (~0.16 lines/cy/CU ~= measured
// 112 G-lines/s). Hardware-structural; only untested lever is a DMA-path
// gather (global_load_lds), high-risk, deferred.

__global__ __launch_bounds__(256) void agg_kernel(const ushort* __restrict__ hb,
                                                  const int* __restrict__ row,
                                                  const int* __restrict__ col,
                                                  ushort* __restrict__ aggB) {
    int t = blockIdx.x * 256 + threadIdx.x;
    int v = t >> 6;
    int lane = t & 63;
    if (v >= N_NODES) return;
    int g = lane >> 4;
    int flOff = (lane & 15) * 16;  // byte offset of this lane's 16B chunk
    int beg = row[v], end = row[v + 1];
    int deg = end - beg;
    float a0 = 0.f, a1 = 0.f, a2 = 0.f, a3 = 0.f;
    float a4 = 0.f, a5 = 0.f, a6 = 0.f, a7 = 0.f;
    const char* hp = (const char*)hb;

#define ACC8(p)                                          \
    a0 += lo16f((p).x); a1 += hi16f((p).x);              \
    a2 += lo16f((p).y); a3 += hi16f((p).y);              \
    a4 += lo16f((p).z); a5 += hi16f((p).z);              \
    a6 += lo16f((p).w); a7 += hi16f((p).w);

    int i = beg;
    int end16 = beg + (deg & ~15);
    if (i < end16) {
        int c0 = col[i + g];
        int c1 = col[i + 4 + g];
        int c2 = col[i + 8 + g];
        int c3 = col[i + 12 + g];
        while (true) {
            uint4 p0 = *(const uint4*)(hp + (((unsigned)c0 << 8) | (unsigned)flOff));
            uint4 p1 = *(const uint4*)(hp + (((unsigned)c1 << 8) | (unsigned)flOff));
            uint4 p2 = *(const uint4*)(hp + (((unsigned)c2 << 8) | (unsigned)flOff));
            uint4 p3 = *(const uint4*)(hp + (((unsigned)c3 << 8) | (unsigned)flOff));
            i += 16;
            bool more = i < end16;
            if (more) {
                c0 = col[i + g];
                c1 = col[i + 4 + g];
                c2 = col[i + 8 + g];
                c3 = col[i + 12 + g];
            }
            ACC8(p0);
            ACC8(p1);
            ACC8(p2);
            ACC8(p3);
            if (!more) break;
        }
    }
    if (i + 8 <= end) {
        int c0 = col[i + g];
        int c1 = col[i + 4 + g];
        uint4 p0 = *(const uint4*)(hp + (((unsigned)c0 << 8) | (unsigned)flOff));
        uint4 p1 = *(const uint4*)(hp + (((unsigned)c1 << 8) | (unsigned)flOff));
        ACC8(p0);
        ACC8(p1);
        i += 8;
    }
    if (i + 4 <= end) {
        int c = col[i + g];
        uint4 p = *(const uint4*)(hp + (((unsigned)c << 8) | (unsigned)flOff));
        ACC8(p);
        i += 4;
    }
    if (i < end) {
        int e = i + g;
        bool ok = e < end;
        int c = col[ok ? e : beg];
        uint4 p = *(const uint4*)(hp + (((unsigned)c << 8) | (unsigned)flOff));
        float m = ok ? 1.f : 0.f;
        a0 += m * lo16f(p.x); a1 += m * hi16f(p.x);
        a2 += m * lo16f(p.y); a3 += m * hi16f(p.y);
        a4 += m * lo16f(p.z); a5 += m * hi16f(p.z);
        a6 += m * lo16f(p.w); a7 += m * hi16f(p.w);
    }
#undef ACC8

    // reduce across edge slots (lanes fl, fl+16, fl+32, fl+48)
    a0 += __shfl_xor(a0, 16); a1 += __shfl_xor(a1, 16);
    a2 += __shfl_xor(a2, 16); a3 += __shfl_xor(a3, 16);
    a4 += __shfl_xor(a4, 16); a5 += __shfl_xor(a5, 16);
    a6 += __shfl_xor(a6, 16); a7 += __shfl_xor(a7, 16);
    a0 += __shfl_xor(a0, 32); a1 += __shfl_xor(a1, 32);
    a2 += __shfl_xor(a2, 32); a3 += __shfl_xor(a3, 32);
    a4 += __shfl_xor(a4, 32); a5 += __shfl_xor(a5, 32);
    a6 += __shfl_xor(a6, 32); a7 += __shfl_xor(a7, 32);
    if (g == 0) {
        float invd = 1.0f / (float)(deg > 0 ? deg : 1);
        uint4 o;
        o.x = (unsigned)f2bf(a0 * invd) | ((unsigned)f2bf(a1 * invd) << 16);
        o.y = (unsigned)f2bf(a2 * invd) | ((unsigned)f2bf(a3 * invd) << 16);
        o.z = (unsigned)f2bf(a4 * invd) | ((unsigned)f2bf(a5 * invd) << 16);
        o.w = (unsigned)f2bf(a6 * invd) | ((unsigned)f2bf(a7 * invd) << 16);
        *(uint4*)((char*)aggB + (((size_t)v << 8) | (unsigned)flOff)) = o;
    }
}

// ---------------- combine (layers 1-3): persistent double-buffered pipeline ----------------
// r6's best-measured configuration (64-row tiles, CGRID 512). Unchanged.

__global__ __launch_bounds__(256, 2) void combine_kernel(
    const ushort* __restrict__ hb, const ushort* __restrict__ aggB,
    const ushort* __restrict__ wp,   // [sHi|sLo|nHi|nLo] planes
    const float* __restrict__ bias,
    ushort* __restrict__ outB, int doRelu) {
    __shared__ ushort smemH[2][64 * FEAT];  // 2 x 16KB, swizzled hb tiles
    __shared__ ushort smemA[2][64 * FEAT];  // 2 x 16KB, swizzled aggB tiles
    int tid = threadIdx.x;
    int lane = tid & 63;
    int w = tid >> 6;
    int frow = lane & 15;
    int fq = lane >> 4;
    int fk = fq * 8;
    int nb = w * 32;

    const ushort* sHi = wp;
    const ushort* sLo = wp + 16384;
    const ushort* nHi = wp + 32768;
    const ushort* nLo = wp + 49152;

    // ---- B into registers ONCE: 32 x bf16x8 (128 VGPRs; total 116 measured) ----
    int n0 = nb + frow;
    int n1 = nb + 16 + frow;
    bf16x8 B[4][2][4];
#pragma unroll
    for (int kt = 0; kt < 4; ++kt) {
        int k = kt * 32 + fk;
        B[kt][0][0] = *(const bf16x8*)(sHi + n0 * FEAT + k);
        B[kt][0][1] = *(const bf16x8*)(sLo + n0 * FEAT + k);
        B[kt][0][2] = *(const bf16x8*)(nHi + n0 * FEAT + k);
        B[kt][0][3] = *(const bf16x8*)(nLo + n0 * FEAT + k);
        B[kt][1][0] = *(const bf16x8*)(sHi + n1 * FEAT + k);
        B[kt][1][1] = *(const bf16x8*)(sLo + n1 * FEAT + k);
        B[kt][1][2] = *(const bf16x8*)(nHi + n1 * FEAT + k);
        B[kt][1][3] = *(const bf16x8*)(nLo + n1 * FEAT + k);
    }

    const int nTiles = (N_NODES + 63) / 64;  // 1563
    int tile = blockIdx.x;

    // ---- prologue: stage tile into buf 0 ----
    {
        const char* hpg = (const char*)hb + (size_t)tile * 16384;
        const char* apg = (const char*)aggB + (size_t)tile * 16384;
        char* shH = (char*)smemH[0];
        char* shA = (char*)smemA[0];
#pragma unroll
        for (int c = 0; c < 4; ++c) {
            int chunk = w * 4 + c;
            int d = chunk * 1024 + lane * 16;
            int s = d ^ (((d >> 8) & 7) << 4);  // involution: LDS[x^swz] = G[x]
            GLOAD_LDS16(hpg + s, shH + chunk * 1024);
            GLOAD_LDS16(apg + s, shA + chunk * 1024);
        }
    }
    __syncthreads();  // drains vmcnt(0): prologue DMA + B loads complete

    int buf = 0;
    int swz = (frow & 7) << 4;
    while (true) {
        int next = tile + CGRID;
        // ---- issue next tile's DMA into the other buffer ----
        if (next < nTiles) {
            const char* hpg = (const char*)hb + (size_t)next * 16384;
            const char* apg = (const char*)aggB + (size_t)next * 16384;
            char* shH = (char*)smemH[buf ^ 1];
            char* shA = (char*)smemA[buf ^ 1];
#pragma unroll
            for (int c = 0; c < 4; ++c) {
                int chunk = w * 4 + c;
                int d = chunk * 1024 + lane * 16;
                int s = d ^ (((d >> 8) & 7) << 4);
                GLOAD_LDS16(hpg + s, shH + chunk * 1024);
                GLOAD_LDS16(apg + s, shA + chunk * 1024);
            }
        }

        // ---- compute current tile from smem[buf] ----
        f32x4 acc[4][2];
#pragma unroll
        for (int mt = 0; mt < 4; ++mt)
#pragma unroll
            for (int nt = 0; nt < 2; ++nt) acc[mt][nt] = (f32x4)(0.f);

        {
            char* shH = (char*)smemH[buf];
            char* shA = (char*)smemA[buf];
#pragma unroll
            for (int kt = 0; kt < 4; ++kt) {
                int kB = kt * 64 + fq * 16;  // byte offset of this lane's k-chunk
#pragma unroll
                for (int mt = 0; mt < 4; ++mt) {
                    int off = (((mt * 16 + frow) << 8) + kB) ^ swz;
                    bf16x8 Ah = *(const bf16x8*)(shH + off);
                    bf16x8 Aa = *(const bf16x8*)(shA + off);
#pragma unroll
                    for (int nt = 0; nt < 2; ++nt) {
                        f32x4 c = acc[mt][nt];
                        c = MFMA(Ah, B[kt][nt][0], c);
                        c = MFMA(Ah, B[kt][nt][1], c);
                        c = MFMA(Aa, B[kt][nt][2], c);
                        c = MFMA(Aa, B[kt][nt][3], c);
                        acc[mt][nt] = c;
                    }
                }
            }
        }

        // ---- epilogue for current tile ----
        int v0 = tile * 64;
#pragma unroll
        for (int nt = 0; nt < 2; ++nt) {
            int colo = nb + nt * 16 + (lane & 15);
            float b = bias[colo];
#pragma unroll
            for (int mt = 0; mt < 4; ++mt) {
#pragma unroll
                for (int i = 0; i < 4; ++i) {
                    int v = v0 + mt * 16 + (lane >> 4) * 4 + i;
                    if (v >= N_NODES) continue;
                    float r = acc[mt][nt][i] + b;
                    if (doRelu) r = fmaxf(r, 0.f);
                    outB[(size_t)v * FEAT + colo] = f2bf(r);
                }
            }
        }

        if (next >= nTiles) break;
        __syncthreads();  // next-tile DMA landed; smem[buf] free for re-stage
        buf ^= 1;
        tile = next;
    }
}

// ---------------- layer 4: persistent project-then-aggregate ----------------

__global__ __launch_bounds__(256, 2) void proj_kernel(
    const ushort* __restrict__ hb, const ushort* __restrict__ wn,
    ushort* __restrict__ pbuf) {
    __shared__ ushort smem[2][128 * FEAT];  // 2 x 32KB, swizzled hb tiles
    int tid = threadIdx.x;
    int lane = tid & 63;
    int w = tid >> 6;
    int rh = w >> 1;          // row-half (0: rows 0-63, 1: rows 64-127)
    int nb = (w & 1) * 32;    // col-half of the 64 weight rows
    int frow = lane & 15;
    int fq = lane >> 4;
    int fk = fq * 8;
    const ushort* nHi = wn;
    const ushort* nLo = wn + 16384;

    int n0 = nb + frow;
    int n1 = nb + 16 + frow;
    bf16x8 B[4][2][2];
#pragma unroll
    for (int kt = 0; kt < 4; ++kt) {
        int k = kt * 32 + fk;
        B[kt][0][0] = *(const bf16x8*)(nHi + n0 * FEAT + k);
        B[kt][0][1] = *(const bf16x8*)(nLo + n0 * FEAT + k);
        B[kt][1][0] = *(const bf16x8*)(nHi + n1 * FEAT + k);
        B[kt][1][1] = *(const bf16x8*)(nLo + n1 * FEAT + k);
    }

    const int nTiles = (N_NODES + 127) / 128;  // 782
    int tile = blockIdx.x;

    {
        const char* hpg = (const char*)hb + (size_t)tile * 32768;
        char* sh = (char*)smem[0];
#pragma unroll
        for (int c = 0; c < 8; ++c) {
            int chunk = w * 8 + c;
            int d = chunk * 1024 + lane * 16;
            int s = d ^ (((d >> 8) & 7) << 4);
            GLOAD_LDS16(hpg + s, sh + chunk * 1024);
        }
    }
    __syncthreads();

    int buf = 0;
    int swz = (frow & 7) << 4;
    while (true) {
        int next = tile + CGRID;
        if (next < nTiles) {
            const char* hpg = (const char*)hb + (size_t)next * 32768;
            char* sh = (char*)smem[buf ^ 1];
#pragma unroll
            for (int c = 0; c < 8; ++c) {
                int chunk = w * 8 + c;
                int d = chunk * 1024 + lane * 16;
                int s = d ^ (((d >> 8) & 7) << 4);
                GLOAD_LDS16(hpg + s, sh + chunk * 1024);
            }
        }

        f32x4 acc[4][2];
#pragma unroll
        for (int mt = 0; mt < 4; ++mt)
#pragma unroll
            for (int nt = 0; nt < 2; ++nt) acc[mt][nt] = (f32x4)(0.f);

        {
            char* sh = (char*)smem[buf];
#pragma unroll
            for (int kt = 0; kt < 4; ++kt) {
                int kB = kt * 64 + fq * 16;
#pragma unroll
                for (int mt = 0; mt < 4; ++mt) {
                    int r = rh * 64 + mt * 16 + frow;
                    int off = ((r << 8) + kB) ^ swz;
                    bf16x8 Ah = *(const bf16x8*)(sh + off);
                    f32x4 c0 = acc[mt][0];
                    c0 = MFMA(Ah, B[kt][0][0], c0);
                    c0 = MFMA(Ah, B[kt][0][1], c0);
                    acc[mt][0] = c0;
                    f32x4 c1 = acc[mt][1];
                    c1 = MFMA(Ah, B[kt][1][0], c1);
                    c1 = MFMA(Ah, B[kt][1][1], c1);
                    acc[mt][1] = c1;
                }
            }
        }

        int v0 = tile * 128 + rh * 64;
#pragma unroll
        for (int nt = 0; nt < 2; ++nt) {
            int colo = nb + nt * 16 + (lane & 15);
            if (colo < 40) {
#pragma unroll
                for (int mt = 0; mt < 4; ++mt) {
#pragma unroll
                    for (int i = 0; i < 4; ++i) {
                        int v = v0 + mt * 16 + (lane >> 4) * 4 + i;
                        if (v >= N_NODES) continue;
                        pbuf[(size_t)v * 40 + colo] = f2bf(acc[mt][nt][i]);
                    }
                }
            }
        }

        if (next >= nTiles) break;
        __syncthreads();
        buf ^= 1;
        tile = next;
    }
}

// agg4: 20-lane groups, 12 nodes per 256-thread block (lane eff 62.5% -> 93.8%).
// Same per-node loop and add order as r11 -> bit-identical.
__global__ __launch_bounds__(256) void agg4_kernel(const ushort* __restrict__ pbuf,
                                                   const int* __restrict__ row,
                                                   const int* __restrict__ col,
                                                   float* __restrict__ aggP) {
    int t = threadIdx.x;
    if (t >= 240) return;
    int v = blockIdx.x * 12 + t / 20;
    int l = t % 20;
    if (v >= N_NODES) return;
    int beg = row[v], end = row[v + 1];
    const unsigned int* base = (const unsigned int*)pbuf;
    float s0 = 0.f, s1 = 0.f;
    int i = beg;
    for (; i + 4 <= end; i += 4) {
        int c0 = col[i], c1 = col[i + 1], c2 = col[i + 2], c3 = col[i + 3];
        unsigned int p0 = base[(size_t)c0 * 20 + l];
        unsigned int p1 = base[(size_t)c1 * 20 + l];
        unsigned int p2 = base[(size_t)c2 * 20 + l];
        unsigned int p3 = base[(size_t)c3 * 20 + l];
        s0 += lo16f(p0); s1 += hi16f(p0);
        s0 += lo16f(p1); s1 += hi16f(p1);
        s0 += lo16f(p2); s1 += hi16f(p2);
        s0 += lo16f(p3); s1 += hi16f(p3);
    }
    for (; i < end; ++i) {
        unsigned int p = base[(size_t)col[i] * 20 + l];
        s0 += lo16f(p); s1 += hi16f(p);
    }
    int deg = end - beg;
    float invd = 1.0f / (float)(deg > 0 ? deg : 1);
    float2 o; o.x = s0 * invd; o.y = s1 * invd;
    *(float2*)(aggP + (size_t)v * 40 + 2 * l) = o;
}

__global__ __launch_bounds__(256, 2) void combine4_kernel(
    const ushort* __restrict__ hb, const ushort* __restrict__ ws,
    const float* __restrict__ aggP, const float* __restrict__ bias,
    float* __restrict__ out) {
    __shared__ ushort smem[2][128 * FEAT];  // 2 x 32KB, swizzled hb tiles
    int tid = threadIdx.x;
    int lane = tid & 63;
    int w = tid >> 6;
    int rh = w >> 1;
    int nb = (w & 1) * 32;
    int frow = lane & 15;
    int fq = lane >> 4;
    int fk = fq * 8;
    const ushort* sHi = ws;
    const ushort* sLo = ws + 16384;

    int n0 = nb + frow;
    int n1 = nb + 16 + frow;
    bf16x8 B[4][2][2];
#pragma unroll
    for (int kt = 0; kt < 4; ++kt) {
        int k = kt * 32 + fk;
        B[kt][0][0] = *(const bf16x8*)(sHi + n0 * FEAT + k);
        B[kt][0][1] = *(const bf16x8*)(sLo + n0 * FEAT + k);
        B[kt][1][0] = *(const bf16x8*)(sHi + n1 * FEAT + k);
        B[kt][1][1] = *(const bf16x8*)(sLo + n1 * FEAT + k);
    }

    const int nTiles = (N_NODES + 127) / 128;  // 782
    int tile = blockIdx.x;

    {
        const char* hpg = (const char*)hb + (size_t)tile * 32768;
        char* sh = (char*)smem[0];
#pragma unroll
        for (int c = 0; c < 8; ++c) {
            int chunk = w * 8 + c;
            int d = chunk * 1024 + lane * 16;
            int s = d ^ (((d >> 8) & 7) << 4);
            GLOAD_LDS16(hpg + s, sh + chunk * 1024);
        }
    }
    __syncthreads();

    int buf = 0;
    int swz = (frow & 7) << 4;
    while (true) {
        int next = tile + CGRID;
        if (next < nTiles) {
            const char* hpg = (const char*)hb + (size_t)next * 32768;
            char* sh = (char*)smem[buf ^ 1];
#pragma unroll
            for (int c = 0; c < 8; ++c) {
                int chunk = w * 8 + c;
                int d = chunk * 1024 + lane * 16;
                int s = d ^ (((d >> 8) & 7) << 4);
                GLOAD_LDS16(hpg + s, sh + chunk * 1024);
            }
        }

        f32x4 acc[4][2];
#pragma unroll
        for (int mt = 0; mt < 4; ++mt)
#pragma unroll
            for (int nt = 0; nt < 2; ++nt) acc[mt][nt] = (f32x4)(0.f);

        {
            char* sh = (char*)smem[buf];
#pragma unroll
            for (int kt = 0; kt < 4; ++kt) {
                int kB = kt * 64 + fq * 16;
#pragma unroll
                for (int mt = 0; mt < 4; ++mt) {
                    int r = rh * 64 + mt * 16 + frow;
                    int off = ((r << 8) + kB) ^ swz;
                    bf16x8 Ah = *(const bf16x8*)(sh + off);
                    f32x4 c0 = acc[mt][0];
                    c0 = MFMA(Ah, B[kt][0][0], c0);
                    c0 = MFMA(Ah, B[kt][0][1], c0);
                    acc[mt][0] = c0;
                    f32x4 c1 = acc[mt][1];
                    c1 = MFMA(Ah, B[kt][1][0], c1);
                    c1 = MFMA(Ah, B[kt][1][1], c1);
                    acc[mt][1] = c1;
                }
            }
        }

        int v0 = tile * 128 + rh * 64;
#pragma unroll
        for (int nt = 0; nt < 2; ++nt) {
            int colo = nb + nt * 16 + (lane & 15);
            if (colo < 40) {
                float b = bias[colo];
#pragma unroll
                for (int mt = 0; mt < 4; ++mt) {
#pragma unroll
                    for (int i = 0; i < 4; ++i) {
                        int v = v0 + mt * 16 + (lane >> 4) * 4 + i;
                        if (v >= N_NODES) continue;
                        out[(size_t)v * 40 + colo] = acc[mt][nt][i] + b + aggP[(size_t)v * 40 + colo];
                    }
                }
            }
        }

        if (next >= nTiles) break;
        __syncthreads();
        buf ^= 1;
        tile = next;
    }
}

// ---------------- launch ----------------

static inline size_t align256(size_t x) { return (x + 255) & ~(size_t)255; }

extern "C" void kernel_launch(void* const* d_in, const int* in_sizes, int n_in,
                              void* d_out, int out_size, void* d_ws, size_t ws_size,
                              hipStream_t stream) {
    const float* x = (const float*)d_in[0];
    const int* src = (const int*)d_in[1];
    const int* dst = (const int*)d_in[2];
    const float* ws1 = (const float*)d_in[3];
    const float* wn1 = (const float*)d_in[4];
    const float* b1 = (const float*)d_in[5];
    const float* ws2 = (const float*)d_in[6];
    const float* wn2 = (const float*)d_in[7];
    const float* b2 = (const float*)d_in[8];
    const float* ws3 = (const float*)d_in[9];
    const float* wn3 = (const float*)d_in[10];
    const float* b3 = (const float*)d_in[11];
    const float* ws4 = (const float*)d_in[12];
    const float* wn4 = (const float*)d_in[13];
    const float* b4 = (const float*)d_in[14];
    float* out = (float*)d_out;

    char* base = (char*)d_ws;
    size_t off = 0;
    auto alloc = [&](size_t bytes) -> void* {
        void* p = base + off;
        off = align256(off + bytes);
        return p;
    };
    int* row = (int*)alloc((size_t)(N_NODES + 1) * 4);
    int* gcur = (int*)alloc((size_t)KB * 4);
    int* col = (int*)alloc((size_t)N_EDGES * 4);
    int2* pairs = (int2*)alloc((size_t)KB * BCAP * 8);   // 16.8 MB padded buckets
    ushort* wp = (ushort*)alloc((size_t)8 * 32768 * 2);
    ushort* xb = (ushort*)alloc((size_t)N_NODES * FEAT * 2);
    ushort* bufA = (ushort*)alloc((size_t)N_NODES * FEAT * 2);
    ushort* bufB = (ushort*)alloc((size_t)N_NODES * FEAT * 2);
    ushort* aggB = (ushort*)alloc((size_t)N_NODES * FEAT * 2);
    ushort* pbuf = (ushort*)alloc((size_t)N_NODES * 40 * 2);
    float* aggP = (float*)alloc((size_t)N_NODES * 40 * 4);
    (void)ws_size;

    // frontend (converts + fillA merged) + CSR finish
    hipMemsetAsync(gcur, 0, (size_t)KB * 4, stream);
    frontend_kernel<<<ABLKS + XBLKS + WBLKS, 256, 0, stream>>>(
        x, xb, ws1, wn1, ws2, wn2, ws3, wn3, ws4, wn4, wp, src, dst, gcur, pairs);
    fillB_kernel<<<KB, 512, 0, stream>>>(pairs, gcur, row, col);

    int aggGrid = ((size_t)N_NODES * 64 + 255) / 256;   // 25000

    const ushort* wp1 = wp;
    const ushort* wp2 = wp + (size_t)2 * 32768;
    const ushort* wp3 = wp + (size_t)4 * 32768;
    const ushort* wp4 = wp + (size_t)6 * 32768;

    agg_kernel<<<aggGrid, 256, 0, stream>>>(xb, row, col, aggB);
    combine_kernel<<<CGRID, 256, 0, stream>>>(xb, aggB, wp1, b1, bufA, 1);
    agg_kernel<<<aggGrid, 256, 0, stream>>>(bufA, row, col, aggB);
    combine_kernel<<<CGRID, 256, 0, stream>>>(bufA, aggB, wp2, b2, bufB, 1);
    agg_kernel<<<aggGrid, 256, 0, stream>>>(bufB, row, col, aggB);
    combine_kernel<<<CGRID, 256, 0, stream>>>(bufB, aggB, wp3, b3, bufA, 1);
    // layer 4: project -> aggregate(40-dim) -> self-combine
    proj_kernel<<<CGRID, 256, 0, stream>>>(bufA, wp4 + 32768, pbuf);
    agg4_kernel<<<(N_NODES + 11) / 12, 256, 0, stream>>>(pbuf, row, col, aggP);
    combine4_kernel<<<CGRID, 256, 0, stream>>>(bufA, wp4, aggP, b4, out);
}